// Round 5
// baseline (345.285 us; speedup 1.0000x reference)
//
#include <hip/hip_runtime.h>

typedef unsigned short bf16u;
typedef unsigned char u8;
typedef unsigned int u32;
typedef float f32x4 __attribute__((ext_vector_type(4)));
typedef short bf16x8 __attribute__((ext_vector_type(8)));

__device__ inline float sigmoidf_(float x) { return 1.f / (1.f + __expf(-x)); }
__device__ inline float tanhf_(float x) {
  // fast tanh: 1 - 2/(e^{2x}+1); |err| ~1e-6, saturates correctly at +-inf
  float e = __expf(2.f * x);
  return 1.f - 2.f / (e + 1.f);
}
__device__ inline float b2f(bf16u u) { return __uint_as_float(((u32)u) << 16); }
__device__ inline bf16u f2b(float f) {
  u32 i = __float_as_uint(f);
  u32 r = (i + 0x7fffu + ((i >> 16) & 1u)) >> 16;
  return (bf16u)r;
}
// uint8 table codec: stored = clamp(round(v*512 + 128)); decoded = u/512 - 0.25
__device__ inline u8 enc8(float v) {
  float q = fmaf(v, 512.f, 128.5f);
  q = fminf(fmaxf(q, 0.f), 255.f);
  return (u8)(int)q;
}
__device__ inline float ub0(u32 u) { return (float)(u & 0xffu); }
__device__ inline float ub1(u32 u) { return (float)((u >> 8) & 0xffu); }
__device__ inline float ub2(u32 u) { return (float)((u >> 16) & 0xffu); }
__device__ inline float ub3(u32 u) { return (float)(u >> 24); }

// async global->LDS, 16B per lane; LDS dest is wave-uniform base + lane*16
#define GLOAD16(gsrc, ldst)                                                   \
  __builtin_amdgcn_global_load_lds(                                           \
      (const __attribute__((address_space(1))) void*)(gsrc),                  \
      (__attribute__((address_space(3))) void*)(ldst), 16, 0, 0)

// ---------------------------------------------------------------------------
// k_front: heterogeneous blocks, one launch.
//   blocks 0..1562   : pr/pe table build. v5: uvec computed from the STAGED
//                      bf16 B-tiles in LDS (column dot, 2 lanes/bank = free)
//                      instead of a per-block gcn_w global pass (-205MB L2).
//                      Scores moved after the MFMA passes (need only As+us).
//   blocks 1563..3610: LSTM weight pack (WWa/WWb/bsum) + XX pad-zero.
__global__ __launch_bounds__(256) void k_front(
    const float* __restrict__ emb, const float* __restrict__ gcn_w,
    const float* __restrict__ attn_w,
    const float* __restrict__ w_ih, const float* __restrict__ w_hh,
    const float* __restrict__ b_ih, const float* __restrict__ b_hh,
    u8* __restrict__ pr, u8* __restrict__ pe,
    float* __restrict__ srel, float* __restrict__ sent,
    bf16u* __restrict__ WWa, bf16u* __restrict__ WWb, float* __restrict__ bsum,
    bf16u* __restrict__ XX)
{
  const int blk = blockIdx.x, t = threadIdx.x;
  if (blk >= 1563) {
    const int b = blk - 1563;   // 0..2047
    if (t < 59) {
      XX[(size_t)b * 576 + 517 + t] = 0;
      XX[(size_t)(b + 2048) * 576 + 517 + t] = 0;
    }
    float wi = w_ih[b * 256 + t];
    float wh = w_hh[b * 512 + t];
    WWa[(size_t)b * 576 + t] = f2b(wi);
    WWb[(size_t)b * 576 + t] = f2b(wi + wh);
    WWb[(size_t)b * 576 + 256 + t] = f2b(wh);
    if (t < 59) WWb[(size_t)b * 576 + 517 + t] = 0;
    if (t == 0) bsum[b] = b_ih[b] + b_hh[b];
    return;
  }
  // ---- pr/pe table build ----
  const int row0 = blk << 6;
  __shared__ short As[64][136];
  __shared__ union PB {
    short B[128][136];
    u8 ob[64][272];
  } pb;
  __shared__ float us[256];
  // stage B half 0: pb.B[n][k] = gcn_w[n][k], k<128
  #pragma unroll
  for (int s = 0; s < 8; ++s) {
    int f = s * 256 + t;
    int row = f >> 4, e0 = (f & 15) * 8;
    float4 v0 = *(const float4*)&gcn_w[row * 256 + e0];
    float4 v1 = *(const float4*)&gcn_w[row * 256 + e0 + 4];
    ushort4 p0, p1;
    p0.x = f2b(v0.x); p0.y = f2b(v0.y); p0.z = f2b(v0.z); p0.w = f2b(v0.w);
    p1.x = f2b(v1.x); p1.y = f2b(v1.y); p1.z = f2b(v1.z); p1.w = f2b(v1.w);
    *(ushort4*)&pb.B[row][e0] = p0;
    *(ushort4*)&pb.B[row][e0 + 4] = p1;
  }
  // stage As: emb rows (bf16)
  #pragma unroll
  for (int s = 0; s < 8; ++s) {
    int f = s * 256 + t;
    int row = f >> 5, q = f & 31;
    int gr = row0 + row; if (gr > 100000) gr = 100000;
    float4 v = *(const float4*)&emb[(size_t)gr * 128 + (q << 2)];
    ushort4 pk;
    pk.x = f2b(v.x); pk.y = f2b(v.y); pk.z = f2b(v.z); pk.w = f2b(v.w);
    *(ushort4*)&As[row][q << 2] = pk;
  }
  __syncthreads();
  // us[0..127] from staged B0: us[c] = sum_d B0[d][c]*attn_w[d]
  // (column read: bank = (d*68 + (c>>1)) % 32 -> 2 lanes/bank = free;
  //  attn_w[d] is lane-uniform -> scalar loads)
  if (t < 128) {
    float a = 0.f;
    #pragma unroll 8
    for (int d = 0; d < 128; ++d)
      a = fmaf(__uint_as_float(((u32)(unsigned short)pb.B[d][t]) << 16),
               attn_w[d], a);
    us[t] = a;
  }
  const int wave = t >> 6, lane = t & 63;
  const int quad = lane >> 4, l16 = lane & 15;
  const int wm = (wave >> 1) << 5, wn = (wave & 1) << 6;
  f32x4 acc0[2][4], acc1[2][4];
  #pragma unroll
  for (int i = 0; i < 2; ++i)
    #pragma unroll
    for (int j = 0; j < 4; ++j) {
      acc0[i][j] = (f32x4){0.f, 0.f, 0.f, 0.f};
      acc1[i][j] = (f32x4){0.f, 0.f, 0.f, 0.f};
    }
  #pragma unroll
  for (int kc = 0; kc < 4; ++kc) {
    bf16x8 af[2], bfr[4];
    #pragma unroll
    for (int i = 0; i < 2; ++i)
      af[i] = *(const bf16x8*)&As[wm + i * 16 + l16][kc * 32 + quad * 8];
    #pragma unroll
    for (int j = 0; j < 4; ++j)
      bfr[j] = *(const bf16x8*)&pb.B[wn + j * 16 + l16][kc * 32 + quad * 8];
    #pragma unroll
    for (int i = 0; i < 2; ++i)
      #pragma unroll
      for (int j = 0; j < 4; ++j)
        acc0[i][j] = __builtin_amdgcn_mfma_f32_16x16x32_bf16(af[i], bfr[j], acc0[i][j], 0, 0, 0);
  }
  __syncthreads();
  // stage B half 1: pb.B[n][k] = gcn_w[n][128+k]
  #pragma unroll
  for (int s = 0; s < 8; ++s) {
    int f = s * 256 + t;
    int row = f >> 4, e0 = (f & 15) * 8;
    float4 v0 = *(const float4*)&gcn_w[row * 256 + 128 + e0];
    float4 v1 = *(const float4*)&gcn_w[row * 256 + 128 + e0 + 4];
    ushort4 p0, p1;
    p0.x = f2b(v0.x); p0.y = f2b(v0.y); p0.z = f2b(v0.z); p0.w = f2b(v0.w);
    p1.x = f2b(v1.x); p1.y = f2b(v1.y); p1.z = f2b(v1.z); p1.w = f2b(v1.w);
    *(ushort4*)&pb.B[row][e0] = p0;
    *(ushort4*)&pb.B[row][e0 + 4] = p1;
  }
  __syncthreads();
  // us[128..255] from staged B1 (written this phase, read after next sync)
  if (t < 128) {
    float a = 0.f;
    #pragma unroll 8
    for (int d = 0; d < 128; ++d)
      a = fmaf(__uint_as_float(((u32)(unsigned short)pb.B[d][t]) << 16),
               attn_w[d], a);
    us[128 + t] = a;
  }
  #pragma unroll
  for (int kc = 0; kc < 4; ++kc) {
    bf16x8 af[2], bfr[4];
    #pragma unroll
    for (int i = 0; i < 2; ++i)
      af[i] = *(const bf16x8*)&As[wm + i * 16 + l16][kc * 32 + quad * 8];
    #pragma unroll
    for (int j = 0; j < 4; ++j)
      bfr[j] = *(const bf16x8*)&pb.B[wn + j * 16 + l16][kc * 32 + quad * 8];
    #pragma unroll
    for (int i = 0; i < 2; ++i)
      #pragma unroll
      for (int j = 0; j < 4; ++j)
        acc1[i][j] = __builtin_amdgcn_mfma_f32_16x16x32_bf16(af[i], bfr[j], acc1[i][j], 0, 0, 0);
  }
  __syncthreads();
  // scores (reads As + full us; As never overwritten)
  {
    const int row = t >> 2, l = t & 3;
    int gr = row0 + row; if (gr > 100000) gr = 100000;
    const short* ar = &As[row][l * 32];
    const float* u0 = &us[l * 32];
    const float* u1 = &us[128 + l * 32];
    float p0 = 0.f, p1 = 0.f;
    #pragma unroll
    for (int i = 0; i < 32; ++i) {
      float e = __uint_as_float(((u32)(unsigned short)ar[i]) << 16);
      p0 += e * u0[i];
      p1 += e * u1[i];
    }
    p0 += __shfl_xor(p0, 1, 64); p0 += __shfl_xor(p0, 2, 64);
    p1 += __shfl_xor(p1, 1, 64); p1 += __shfl_xor(p1, 2, 64);
    if (l == 0) { srel[gr] = p0; sent[gr] = p1; }
  }
  // enc8 epilogue -> ob (aliases pb.B; all B reads completed before last sync)
  #pragma unroll
  for (int j = 0; j < 4; ++j) {
    const int col = wn + j * 16 + l16;
    #pragma unroll
    for (int i = 0; i < 2; ++i) {
      #pragma unroll
      for (int r = 0; r < 4; ++r) {
        int row = wm + i * 16 + quad * 4 + r;
        pb.ob[row][col] = enc8(acc0[i][j][r]);
        pb.ob[row][128 + col] = enc8(acc1[i][j][r]);
      }
    }
  }
  __syncthreads();
  #pragma unroll
  for (int s = 0; s < 4; ++s) {
    int c = s * 256 + t;
    int row = c >> 4, part = c & 15;
    int gr = row0 + row;
    if (gr <= 100000) {
      uint4 v = *(const uint4*)&pb.ob[row][part * 16];
      if (part < 8) *(uint4*)&pr[(size_t)gr * 128 + part * 16] = v;
      else          *(uint4*)&pe[(size_t)gr * 128 + (part - 8) * 16] = v;
    }
  }
}

// ---------------------------------------------------------------------------
// Merged neighbor encoder with uint8 tables (at the random 128B-row-gather
// demand-bandwidth floor: 268MB / ~41.5us = 6.45 TB/s delivered).
__global__ __launch_bounds__(256) void k_neighbor(
    const int* __restrict__ q_l1, const int* __restrict__ q_l2,
    const int* __restrict__ q_r1, const int* __restrict__ q_r2,
    const int* __restrict__ s_l1, const int* __restrict__ s_l2,
    const int* __restrict__ s_r1, const int* __restrict__ s_r2,
    const u8* __restrict__ pr, const u8* __restrict__ pe,
    const float* __restrict__ srel, const float* __restrict__ sent,
    const float* __restrict__ gcn_wb, const float* __restrict__ gcn_b,
    const float* __restrict__ hop_gate,
    float* __restrict__ qn, float* __restrict__ sn, bf16u* __restrict__ XX)
{
  const int b = blockIdx.x, t = threadIdx.x;
  const int *cA, *cB; float* outp; bf16u* xxp; int n, coloff;
  if (b < 4096)      { cA = q_l1; cB = q_l2; n = b;        outp = qn; xxp = XX; coloff = 0; }
  else if (b < 8192) { cA = q_r1; cB = q_r2; n = b - 4096; outp = qn; xxp = XX; coloff = 128; }
  else if (b < 8197) { cA = s_l1; cB = s_l2; n = b - 8192; outp = sn; xxp = 0;  coloff = 0; }
  else               { cA = s_r1; cB = s_r2; n = b - 8197; outp = sn; xxp = 0;  coloff = 128; }

  __shared__ float wS[2][64];
  __shared__ float red[256][17];

  const int hop = t >> 7, g = (t >> 3) & 15, p = t & 7;
  const int* connG = hop ? cB : cA;

  int2 pairs[4];
  #pragma unroll
  for (int kk = 0; kk < 4; ++kk)
    pairs[kk] = *(const int2*)&connG[(n * 64 + g + (kk << 4)) * 2];

  float vR = 0.f, vE = 0.f;
  if (t < 128) {
    const int sh = t >> 6, nn = t & 63;
    const int* connS = sh ? cB : cA;
    int2 sp = *(const int2*)&connS[(n * 64 + nn) * 2];
    vR = srel[sp.x];
    vE = sent[sp.y];
  }

  uint4 ra[4], rb[4];
  #pragma unroll
  for (int kk = 0; kk < 4; ++kk) {
    ra[kk] = *(const uint4*)&pr[(size_t)pairs[kk].x * 128 + p * 16];
    rb[kk] = *(const uint4*)&pe[(size_t)pairs[kk].y * 128 + p * 16];
  }

  if (t < 128) {
    const int sh = t >> 6, nn = t & 63;
    float sc = vR + vE;
    float m = sc;
    #pragma unroll
    for (int off = 32; off; off >>= 1) m = fmaxf(m, __shfl_xor(m, off, 64));
    float e = __expf(sc - m);
    float s = e;
    #pragma unroll
    for (int off = 32; off; off >>= 1) s += __shfl_xor(s, off, 64);
    wS[sh][nn] = e / s;
  }
  __syncthreads();

  float a[16];
  #pragma unroll
  for (int c = 0; c < 16; ++c) a[c] = 0.f;
  #pragma unroll
  for (int kk = 0; kk < 4; ++kk) {
    const float wk = wS[hop][g + (kk << 4)];
    const uint4 A = ra[kk], Bv = rb[kk];
    a[0]  += wk * (ub0(A.x) + ub0(Bv.x));
    a[1]  += wk * (ub1(A.x) + ub1(Bv.x));
    a[2]  += wk * (ub2(A.x) + ub2(Bv.x));
    a[3]  += wk * (ub3(A.x) + ub3(Bv.x));
    a[4]  += wk * (ub0(A.y) + ub0(Bv.y));
    a[5]  += wk * (ub1(A.y) + ub1(Bv.y));
    a[6]  += wk * (ub2(A.y) + ub2(Bv.y));
    a[7]  += wk * (ub3(A.y) + ub3(Bv.y));
    a[8]  += wk * (ub0(A.z) + ub0(Bv.z));
    a[9]  += wk * (ub1(A.z) + ub1(Bv.z));
    a[10] += wk * (ub2(A.z) + ub2(Bv.z));
    a[11] += wk * (ub3(A.z) + ub3(Bv.z));
    a[12] += wk * (ub0(A.w) + ub0(Bv.w));
    a[13] += wk * (ub1(A.w) + ub1(Bv.w));
    a[14] += wk * (ub2(A.w) + ub2(Bv.w));
    a[15] += wk * (ub3(A.w) + ub3(Bv.w));
  }
  #pragma unroll
  for (int c = 0; c < 16; ++c) red[t][c] = a[c];
  __syncthreads();

  if (t < 128) {
    const int d = t, pp = d >> 4, cc = d & 15;
    float sA = 0.f, sB = 0.f;
    #pragma unroll
    for (int gg = 0; gg < 16; ++gg) {
      sA += red[gg * 8 + pp][cc];
      sB += red[128 + gg * 8 + pp][cc];
    }
    float accA = sA * (1.f / 512.f) - 0.5f;
    float accB = sB * (1.f / 512.f) - 0.5f;
    float bias = gcn_wb[d] + gcn_b[d];
    float g0 = hop_gate[0], g1 = hop_gate[1];
    float mx = fmaxf(g0, g1);
    float e0 = __expf(g0 - mx), e1 = __expf(g1 - mx);
    float inv = 1.f / (e0 + e1);
    float v = e0 * inv * tanhf_(bias + accA) + e1 * inv * tanhf_(bias + accB);
    outp[n * 256 + coloff + d] = v;
    if (xxp) xxp[(size_t)n * 576 + coloff + d] = f2b(v);
  }
}

// ---------------------------------------------------------------------------
// k_sup = sup1 + sup2 fused (5 blocks): h1 stays in LDS, no global round-trip.
__global__ __launch_bounds__(256) void k_sup(
    const float* __restrict__ sn, const float* __restrict__ p1_w,
    const float* __restrict__ p1_b, const float* __restrict__ p2_w,
    const float* __restrict__ p2_b, const float* __restrict__ ln_g,
    const float* __restrict__ ln_b, float* __restrict__ sg)
{
  const int r = blockIdx.x, t = threadIdx.x;
  const int lane = t & 63, wave = t >> 6;
  __shared__ float xs[256];
  __shared__ float hs[512];
  __shared__ float zs[256];
  __shared__ float r1[4], r2[4];
  xs[t] = sn[r * 256 + t];
  __syncthreads();
  // layer 1: each thread owns outputs j = t and t+256 (256-MAC each; xs
  // reads are LDS broadcasts)
  #pragma unroll
  for (int jj = 0; jj < 2; ++jj) {
    const int j = t + jj * 256;
    const float4* wr = (const float4*)(p1_w + (size_t)j * 256);
    float acc = 0.f;
    #pragma unroll
    for (int k = 0; k < 64; ++k) {
      float4 w = wr[k];
      acc += xs[k * 4] * w.x + xs[k * 4 + 1] * w.y +
             xs[k * 4 + 2] * w.z + xs[k * 4 + 3] * w.w;
    }
    hs[j] = fmaxf(acc + p1_b[j], 0.f);
  }
  __syncthreads();
  // layer 2 + residual
  const int q = t & 3;
  #pragma unroll
  for (int jc = 0; jc < 4; ++jc) {
    int j = jc * 64 + (t >> 2);
    const float* wr = p2_w + (size_t)j * 512 + q * 128;
    float acc = 0.f;
    #pragma unroll
    for (int k = 0; k < 128; ++k) acc += hs[q * 128 + k] * wr[k];
    acc += __shfl_xor(acc, 1, 64);
    acc += __shfl_xor(acc, 2, 64);
    if (q == 0) zs[j] = acc + p2_b[j] + xs[j];
  }
  __syncthreads();
  // layernorm
  float v = zs[t];
  float s1 = v, s2 = v * v;
  #pragma unroll
  for (int off = 32; off; off >>= 1) { s1 += __shfl_xor(s1, off, 64); s2 += __shfl_xor(s2, off, 64); }
  if (lane == 0) { r1[wave] = s1; r2[wave] = s2; }
  __syncthreads();
  float S1 = r1[0] + r1[1] + r1[2] + r1[3];
  float S2 = r2[0] + r2[1] + r2[2] + r2[3];
  float mu = S1 * (1.f / 256.f);
  float var = S2 * (1.f / 256.f) - mu * mu;
  sg[r * 256 + t] = (v - mu) * rsqrtf(var + 1e-6f) * ln_g[t] + ln_b[t];
}

// ---------------------------------------------------------------------------
// gates (bf16, stride 2048, cols 0..1791) = XX @ WW.T + bsum, MFMA 16x16x32.
// BK=64, gload_lds direct staging (rule #21: linear LDS dest + inverse-
// swizzled global source + same-involution ds_read). LDS 64KB (2 blocks/CU;
// grid 448 needs 1.75). v5: sg2 folded in as a block-uniform prologue on
// blocks 0..31 of the step-0 launch (WWb/sm consumed only by LATER launches
// -> race-free; overlay LDS on As, barrier before staging).
__global__ __launch_bounds__(256) void k_gates_mfma(
    const bf16u* __restrict__ XX, const bf16u* __restrict__ WW,
    const float* __restrict__ bsum, bf16u* __restrict__ gates, int kchunks,
    const float* __restrict__ sg, const float* __restrict__ w_hh,
    bf16u* __restrict__ WWbo, float* __restrict__ sm, int dosg2)
{
  const int t = threadIdx.x;
  const int wave = t >> 6, lane = t & 63;
  const int quad = lane >> 4, l16 = lane & 15;
  const int wm = (wave >> 1) << 6, wn = (wave & 1) << 6;
  const int lin = (blockIdx.x & 7) * 56 + (blockIdx.x >> 3);
  const int row0 = (lin / 14) << 7;
  const int col0 = (lin % 14) << 7;
  __shared__ short As[2][128][64];
  __shared__ short Bs[2][128][64];

  if (dosg2 && blockIdx.x < 32) {   // block-uniform branch: barriers legal
    float (*s5)[256] = (float(*)[256])&As[0][0][0];   // 5KB overlay on As
    const int blk = blockIdx.x;
    for (int i = t; i < 1280; i += 256) s5[i >> 8][i & 255] = sg[i];
    __syncthreads();
    if (blk == 0)
      sm[t] = (s5[0][t] + s5[1][t] + s5[2][t] + s5[3][t] + s5[4][t]) * 0.2f;
    const int j = (blk << 6) + (t >> 2), q = t & 3;
    const float4* wr = (const float4*)(w_hh + (size_t)j * 512 + 256 + q * 64);
    float a[5] = {0.f, 0.f, 0.f, 0.f, 0.f};
    #pragma unroll
    for (int kk = 0; kk < 16; ++kk) {
      float4 w = wr[kk];
      int k = q * 64 + kk * 4;
      #pragma unroll
      for (int r = 0; r < 5; ++r)
        a[r] += s5[r][k] * w.x + s5[r][k+1] * w.y + s5[r][k+2] * w.z + s5[r][k+3] * w.w;
    }
    #pragma unroll
    for (int r = 0; r < 5; ++r) {
      a[r] += __shfl_xor(a[r], 1, 64);
      a[r] += __shfl_xor(a[r], 2, 64);
    }
    if (q == 0) {
      #pragma unroll
      for (int r = 0; r < 5; ++r)
        WWbo[(size_t)j * 576 + 512 + r] = f2b(a[r]);
    }
    __syncthreads();   // protect overlay before staging overwrites As
  }

  f32x4 acc[4][4];
  #pragma unroll
  for (int i = 0; i < 4; ++i)
    #pragma unroll
    for (int j = 0; j < 4; ++j) acc[i][j] = (f32x4){0.f, 0.f, 0.f, 0.f};

  int offX[4], offW[4];
  #pragma unroll
  for (int e = 0; e < 4; ++e) {
    int row = wave * 32 + e * 8 + (lane >> 3);
    int sw = (lane & 7) ^ (lane >> 3);
    offX[e] = (row0 + row) * 576 + sw * 8;
    offW[e] = (col0 + row) * 576 + sw * 8;
  }
  char* aBase = (char*)&As[0][0][0] + wave * 4096;
  char* bBase = (char*)&Bs[0][0][0] + wave * 4096;

  #define STAGE(buf, kc)                                                      \
    {                                                                         \
      const int kof_ = (kc) * 64;                                             \
      _Pragma("unroll")                                                       \
      for (int e = 0; e < 4; ++e) {                                           \
        GLOAD16(XX + offX[e] + kof_, aBase + (buf) * 16384 + e * 1024);       \
        GLOAD16(WW + offW[e] + kof_, bBase + (buf) * 16384 + e * 1024);       \
      }                                                                       \
    }

  STAGE(0, 0);
  __syncthreads();   // drains vmcnt -> buf 0 visible

  for (int kc = 0; kc < kchunks; ++kc) {
    const int cur = kc & 1;
    if (kc + 1 < kchunks) STAGE(cur ^ 1, kc + 1);
    #pragma unroll
    for (int kc2 = 0; kc2 < 2; ++kc2) {
      bf16x8 af[4], bfr[4];
      #pragma unroll
      for (int i = 0; i < 4; ++i)
        af[i] = *(const bf16x8*)&As[cur][wm + i * 16 + l16]
                                       [(((kc2 << 2) + quad) ^ (l16 & 7)) << 3];
      #pragma unroll
      for (int j = 0; j < 4; ++j)
        bfr[j] = *(const bf16x8*)&Bs[cur][wn + j * 16 + l16]
                                        [(((kc2 << 2) + quad) ^ (l16 & 7)) << 3];
      #pragma unroll
      for (int i = 0; i < 4; ++i)
        #pragma unroll
        for (int j = 0; j < 4; ++j)
          acc[i][j] = __builtin_amdgcn_mfma_f32_16x16x32_bf16(af[i], bfr[j], acc[i][j], 0, 0, 0);
    }
    __syncthreads();
  }
  #undef STAGE

  #pragma unroll
  for (int j = 0; j < 4; ++j) {
    const int col = col0 + wn + j * 16 + l16;
    const float bs = bsum[col];
    #pragma unroll
    for (int i = 0; i < 4; ++i) {
      #pragma unroll
      for (int r = 0; r < 4; ++r) {
        int row = row0 + wm + i * 16 + quad * 4 + r;
        gates[(size_t)row * 2048 + col] = f2b(acc[i][j][r] + bs);
      }
    }
  }
}

// ---------------------------------------------------------------------------
// Cell pointwise + attention (fused 5-way reduction, 1 barrier).
// Step 3 skips the dead c-store.
__global__ __launch_bounds__(256) void k_cell(
    const bf16u* __restrict__ gates, const float* __restrict__ qn,
    float* __restrict__ c, bf16u* __restrict__ XX,
    const float* __restrict__ sg, const float* __restrict__ sm,
    float* __restrict__ out, int step)
{
  __shared__ float red[4][6];
  const int b = blockIdx.x, t = threadIdx.x;
  const int lane = t & 63, wave = t >> 6;
  const bf16u* g = gates + (size_t)b * 2048;
  float i0 = b2f(g[t]),       f0 = b2f(g[512 + t]), gg0 = b2f(g[1024 + t]), o0 = b2f(g[1536 + t]);
  float i1 = b2f(g[256 + t]), f1 = b2f(g[768 + t]), gg1 = b2f(g[1280 + t]);
  float co0 = step ? c[b * 512 + t] : 0.f;
  float co1 = step ? c[b * 512 + 256 + t] : 0.f;
  float c0 = sigmoidf_(f0) * co0 + sigmoidf_(i0) * tanhf_(gg0);
  float c1 = sigmoidf_(f1) * co1 + sigmoidf_(i1) * tanhf_(gg1);
  if (step < 3) {
    c[b * 512 + t] = c0;
    c[b * 512 + 256 + t] = c1;
  }
  float hcv = sigmoidf_(o0) * tanhf_(c0);
  float h = qn[b * 256 + t] + hcv;
  if (step < 3) {
    XX[(size_t)b * 576 + 256 + t] = f2b(hcv);
    float dots[5];
    #pragma unroll
    for (int s = 0; s < 5; ++s) dots[s] = h * sg[s * 256 + t];
    #pragma unroll
    for (int off = 32; off; off >>= 1) {
      #pragma unroll
      for (int s = 0; s < 5; ++s) dots[s] += __shfl_xor(dots[s], off, 64);
    }
    if (lane == 0) {
      #pragma unroll
      for (int s = 0; s < 5; ++s) red[wave][s] = dots[s];
    }
    __syncthreads();
    #pragma unroll
    for (int s = 0; s < 5; ++s)
      dots[s] = red[0][s] + red[1][s] + red[2][s] + red[3][s];
    float m = dots[0];
    #pragma unroll
    for (int s = 1; s < 5; ++s) m = fmaxf(m, dots[s]);
    float sum = 0.f;
    #pragma unroll
    for (int s = 0; s < 5; ++s) sum += __expf(dots[s] - m);
    if (t < 5) {
      float dv = (t == 1) ? dots[1] : (t == 2) ? dots[2] : (t == 3) ? dots[3]
               : (t == 4) ? dots[4] : dots[0];
      XX[(size_t)b * 576 + 512 + t] = f2b(__expf(dv - m) / sum);
    }
  } else {
    float v = h * sm[t];
    #pragma unroll
    for (int off = 32; off; off >>= 1) v += __shfl_xor(v, off, 64);
    if (lane == 0) red[wave][0] = v;
    __syncthreads();
    if (t == 0) out[b] = red[0][0] + red[1][0] + red[2][0] + red[3][0];
  }
}

// ---------------------------------------------------------------------------
extern "C" void kernel_launch(void* const* d_in, const int* in_sizes, int n_in,
                              void* d_out, int out_size, void* d_ws, size_t ws_size,
                              hipStream_t stream)
{
  (void)in_sizes; (void)n_in; (void)out_size; (void)ws_size;
  const int *q_l1 = (const int*)d_in[0], *q_l2 = (const int*)d_in[1];
  const int *q_r1 = (const int*)d_in[2], *q_r2 = (const int*)d_in[3];
  const int *s_l1 = (const int*)d_in[4], *s_l2 = (const int*)d_in[5];
  const int *s_r1 = (const int*)d_in[6], *s_r2 = (const int*)d_in[7];
  const float* emb      = (const float*)d_in[12];
  const float* gcn_w    = (const float*)d_in[13];
  const float* gcn_wb   = (const float*)d_in[14];
  const float* gcn_b    = (const float*)d_in[15];
  const float* hop_gate = (const float*)d_in[16];
  const float* attn_w   = (const float*)d_in[17];
  const float* p1_w = (const float*)d_in[19];
  const float* p1_b = (const float*)d_in[20];
  const float* p2_w = (const float*)d_in[21];
  const float* p2_b = (const float*)d_in[22];
  const float* ln_g = (const float*)d_in[23];
  const float* ln_b = (const float*)d_in[24];
  const float* w_ih = (const float*)d_in[25];
  const float* w_hh = (const float*)d_in[26];
  const float* b_ih = (const float*)d_in[27];
  const float* b_hh = (const float*)d_in[28];

  char* base = (char*)d_ws;
  size_t off = 0;
  auto alloc = [&](size_t bytes) -> char* {
    char* r = base + off;
    off = (off + bytes + 255) & ~(size_t)255;
    return r;
  };
  u8* pr       = (u8*)alloc(100001ull * 128);
  u8* pe       = (u8*)alloc(100001ull * 128);
  float* srel  = (float*)alloc(100001ull * 4);
  float* sent  = (float*)alloc(100001ull * 4);
  float* qn    = (float*)alloc(4096ull * 256 * 4);
  float* sn    = (float*)alloc(5 * 256 * 4);
  float* sg    = (float*)alloc(5 * 256 * 4);
  float* sm    = (float*)alloc(256 * 4);
  bf16u* XX    = (bf16u*)alloc(4096ull * 576 * 2);
  bf16u* WWa   = (bf16u*)alloc(2048ull * 576 * 2);
  bf16u* WWb   = (bf16u*)alloc(2048ull * 576 * 2);
  float* bsum  = (float*)alloc(2048 * 4);
  bf16u* gates = (bf16u*)alloc(4096ull * 2048 * 2);
  float* cbuf  = (float*)alloc(4096ull * 512 * 4);

  k_front<<<3611, 256, 0, stream>>>(emb, gcn_w, attn_w, w_ih, w_hh, b_ih, b_hh,
                                    pr, pe, srel, sent, WWa, WWb, bsum, XX);
  k_neighbor<<<8202, 256, 0, stream>>>(q_l1, q_l2, q_r1, q_r2, s_l1, s_l2, s_r1, s_r2,
                                       pr, pe, srel, sent, gcn_wb, gcn_b, hop_gate,
                                       qn, sn, XX);
  k_sup<<<5, 256, 0, stream>>>(sn, p1_w, p1_b, p2_w, p2_b, ln_g, ln_b, sg);

  for (int step = 0; step < 4; ++step) {
    if (step == 0)
      k_gates_mfma<<<448, 256, 0, stream>>>(XX, WWa, bsum, gates, 4,
                                            sg, w_hh, WWb, sm, 1);
    else
      k_gates_mfma<<<448, 256, 0, stream>>>(XX, WWb, bsum, gates, 9,
                                            sg, w_hh, WWb, sm, 0);
    k_cell<<<4096, 256, 0, stream>>>(gates, qn, cbuf, XX, sg, sm, (float*)d_out, step);
  }
}

// Round 6
// 332.797 us; speedup vs baseline: 1.0375x; 1.0375x over previous
//
#include <hip/hip_runtime.h>

typedef unsigned short bf16u;
typedef unsigned char u8;
typedef unsigned int u32;
typedef float f32x4 __attribute__((ext_vector_type(4)));
typedef short bf16x8 __attribute__((ext_vector_type(8)));

__device__ inline float sigmoidf_(float x) { return 1.f / (1.f + __expf(-x)); }
__device__ inline float tanhf_(float x) {
  // fast tanh: 1 - 2/(e^{2x}+1); |err| ~1e-6, saturates correctly at +-inf
  float e = __expf(2.f * x);
  return 1.f - 2.f / (e + 1.f);
}
__device__ inline float b2f(bf16u u) { return __uint_as_float(((u32)u) << 16); }
__device__ inline bf16u f2b(float f) {
  u32 i = __float_as_uint(f);
  u32 r = (i + 0x7fffu + ((i >> 16) & 1u)) >> 16;
  return (bf16u)r;
}
// uint8 table codec: stored = clamp(round(v*512 + 128)); decoded = u/512 - 0.25
__device__ inline u8 enc8(float v) {
  float q = fmaf(v, 512.f, 128.5f);
  q = fminf(fmaxf(q, 0.f), 255.f);
  return (u8)(int)q;
}
__device__ inline float ub0(u32 u) { return (float)(u & 0xffu); }
__device__ inline float ub1(u32 u) { return (float)((u >> 8) & 0xffu); }
__device__ inline float ub2(u32 u) { return (float)((u >> 16) & 0xffu); }
__device__ inline float ub3(u32 u) { return (float)(u >> 24); }

// async global->LDS, 16B per lane; LDS dest is wave-uniform base + lane*16
#define GLOAD16(gsrc, ldst)                                                   \
  __builtin_amdgcn_global_load_lds(                                           \
      (const __attribute__((address_space(1))) void*)(gsrc),                  \
      (__attribute__((address_space(3))) void*)(ldst), 16, 0, 0)

// ---------------------------------------------------------------------------
// k_front: heterogeneous blocks, one launch.
//   blocks 0..1562   : pr/pe table build (uvec from staged bf16 B-tiles;
//                      scores after the MFMA passes)
//   blocks 1563..3610: LSTM weight pack (WWa/WWb/bsum) + XX pad-zero.
__global__ __launch_bounds__(256) void k_front(
    const float* __restrict__ emb, const float* __restrict__ gcn_w,
    const float* __restrict__ attn_w,
    const float* __restrict__ w_ih, const float* __restrict__ w_hh,
    const float* __restrict__ b_ih, const float* __restrict__ b_hh,
    u8* __restrict__ pr, u8* __restrict__ pe,
    float* __restrict__ srel, float* __restrict__ sent,
    bf16u* __restrict__ WWa, bf16u* __restrict__ WWb, float* __restrict__ bsum,
    bf16u* __restrict__ XX)
{
  const int blk = blockIdx.x, t = threadIdx.x;
  if (blk >= 1563) {
    const int b = blk - 1563;   // 0..2047
    if (t < 59) {
      XX[(size_t)b * 576 + 517 + t] = 0;
      XX[(size_t)(b + 2048) * 576 + 517 + t] = 0;
    }
    float wi = w_ih[b * 256 + t];
    float wh = w_hh[b * 512 + t];
    WWa[(size_t)b * 576 + t] = f2b(wi);
    WWb[(size_t)b * 576 + t] = f2b(wi + wh);
    WWb[(size_t)b * 576 + 256 + t] = f2b(wh);
    if (t < 59) WWb[(size_t)b * 576 + 517 + t] = 0;
    if (t == 0) bsum[b] = b_ih[b] + b_hh[b];
    return;
  }
  // ---- pr/pe table build ----
  const int row0 = blk << 6;
  __shared__ short As[64][136];
  __shared__ union PB {
    short B[128][136];
    u8 ob[64][272];
  } pb;
  __shared__ float us[256];
  // stage B half 0: pb.B[n][k] = gcn_w[n][k], k<128
  #pragma unroll
  for (int s = 0; s < 8; ++s) {
    int f = s * 256 + t;
    int row = f >> 4, e0 = (f & 15) * 8;
    float4 v0 = *(const float4*)&gcn_w[row * 256 + e0];
    float4 v1 = *(const float4*)&gcn_w[row * 256 + e0 + 4];
    ushort4 p0, p1;
    p0.x = f2b(v0.x); p0.y = f2b(v0.y); p0.z = f2b(v0.z); p0.w = f2b(v0.w);
    p1.x = f2b(v1.x); p1.y = f2b(v1.y); p1.z = f2b(v1.z); p1.w = f2b(v1.w);
    *(ushort4*)&pb.B[row][e0] = p0;
    *(ushort4*)&pb.B[row][e0 + 4] = p1;
  }
  // stage As: emb rows (bf16)
  #pragma unroll
  for (int s = 0; s < 8; ++s) {
    int f = s * 256 + t;
    int row = f >> 5, q = f & 31;
    int gr = row0 + row; if (gr > 100000) gr = 100000;
    float4 v = *(const float4*)&emb[(size_t)gr * 128 + (q << 2)];
    ushort4 pk;
    pk.x = f2b(v.x); pk.y = f2b(v.y); pk.z = f2b(v.z); pk.w = f2b(v.w);
    *(ushort4*)&As[row][q << 2] = pk;
  }
  __syncthreads();
  // us[0..127] from staged B0 (column read: 2 lanes/bank = free)
  if (t < 128) {
    float a = 0.f;
    #pragma unroll 8
    for (int d = 0; d < 128; ++d)
      a = fmaf(__uint_as_float(((u32)(unsigned short)pb.B[d][t]) << 16),
               attn_w[d], a);
    us[t] = a;
  }
  const int wave = t >> 6, lane = t & 63;
  const int quad = lane >> 4, l16 = lane & 15;
  const int wm = (wave >> 1) << 5, wn = (wave & 1) << 6;
  f32x4 acc0[2][4], acc1[2][4];
  #pragma unroll
  for (int i = 0; i < 2; ++i)
    #pragma unroll
    for (int j = 0; j < 4; ++j) {
      acc0[i][j] = (f32x4){0.f, 0.f, 0.f, 0.f};
      acc1[i][j] = (f32x4){0.f, 0.f, 0.f, 0.f};
    }
  #pragma unroll
  for (int kc = 0; kc < 4; ++kc) {
    bf16x8 af[2], bfr[4];
    #pragma unroll
    for (int i = 0; i < 2; ++i)
      af[i] = *(const bf16x8*)&As[wm + i * 16 + l16][kc * 32 + quad * 8];
    #pragma unroll
    for (int j = 0; j < 4; ++j)
      bfr[j] = *(const bf16x8*)&pb.B[wn + j * 16 + l16][kc * 32 + quad * 8];
    #pragma unroll
    for (int i = 0; i < 2; ++i)
      #pragma unroll
      for (int j = 0; j < 4; ++j)
        acc0[i][j] = __builtin_amdgcn_mfma_f32_16x16x32_bf16(af[i], bfr[j], acc0[i][j], 0, 0, 0);
  }
  __syncthreads();
  // stage B half 1: pb.B[n][k] = gcn_w[n][128+k]
  #pragma unroll
  for (int s = 0; s < 8; ++s) {
    int f = s * 256 + t;
    int row = f >> 4, e0 = (f & 15) * 8;
    float4 v0 = *(const float4*)&gcn_w[row * 256 + 128 + e0];
    float4 v1 = *(const float4*)&gcn_w[row * 256 + 128 + e0 + 4];
    ushort4 p0, p1;
    p0.x = f2b(v0.x); p0.y = f2b(v0.y); p0.z = f2b(v0.z); p0.w = f2b(v0.w);
    p1.x = f2b(v1.x); p1.y = f2b(v1.y); p1.z = f2b(v1.z); p1.w = f2b(v1.w);
    *(ushort4*)&pb.B[row][e0] = p0;
    *(ushort4*)&pb.B[row][e0 + 4] = p1;
  }
  __syncthreads();
  // us[128..255] from staged B1
  if (t < 128) {
    float a = 0.f;
    #pragma unroll 8
    for (int d = 0; d < 128; ++d)
      a = fmaf(__uint_as_float(((u32)(unsigned short)pb.B[d][t]) << 16),
               attn_w[d], a);
    us[128 + t] = a;
  }
  #pragma unroll
  for (int kc = 0; kc < 4; ++kc) {
    bf16x8 af[2], bfr[4];
    #pragma unroll
    for (int i = 0; i < 2; ++i)
      af[i] = *(const bf16x8*)&As[wm + i * 16 + l16][kc * 32 + quad * 8];
    #pragma unroll
    for (int j = 0; j < 4; ++j)
      bfr[j] = *(const bf16x8*)&pb.B[wn + j * 16 + l16][kc * 32 + quad * 8];
    #pragma unroll
    for (int i = 0; i < 2; ++i)
      #pragma unroll
      for (int j = 0; j < 4; ++j)
        acc1[i][j] = __builtin_amdgcn_mfma_f32_16x16x32_bf16(af[i], bfr[j], acc1[i][j], 0, 0, 0);
  }
  __syncthreads();
  // scores (reads As + full us; As never overwritten)
  {
    const int row = t >> 2, l = t & 3;
    int gr = row0 + row; if (gr > 100000) gr = 100000;
    const short* ar = &As[row][l * 32];
    const float* u0 = &us[l * 32];
    const float* u1 = &us[128 + l * 32];
    float p0 = 0.f, p1 = 0.f;
    #pragma unroll
    for (int i = 0; i < 32; ++i) {
      float e = __uint_as_float(((u32)(unsigned short)ar[i]) << 16);
      p0 += e * u0[i];
      p1 += e * u1[i];
    }
    p0 += __shfl_xor(p0, 1, 64); p0 += __shfl_xor(p0, 2, 64);
    p1 += __shfl_xor(p1, 1, 64); p1 += __shfl_xor(p1, 2, 64);
    if (l == 0) { srel[gr] = p0; sent[gr] = p1; }
  }
  // enc8 epilogue -> ob (aliases pb.B; all B reads completed before last sync)
  #pragma unroll
  for (int j = 0; j < 4; ++j) {
    const int col = wn + j * 16 + l16;
    #pragma unroll
    for (int i = 0; i < 2; ++i) {
      #pragma unroll
      for (int r = 0; r < 4; ++r) {
        int row = wm + i * 16 + quad * 4 + r;
        pb.ob[row][col] = enc8(acc0[i][j][r]);
        pb.ob[row][128 + col] = enc8(acc1[i][j][r]);
      }
    }
  }
  __syncthreads();
  #pragma unroll
  for (int s = 0; s < 4; ++s) {
    int c = s * 256 + t;
    int row = c >> 4, part = c & 15;
    int gr = row0 + row;
    if (gr <= 100000) {
      uint4 v = *(const uint4*)&pb.ob[row][part * 16];
      if (part < 8) *(uint4*)&pr[(size_t)gr * 128 + part * 16] = v;
      else          *(uint4*)&pe[(size_t)gr * 128 + (part - 8) * 16] = v;
    }
  }
}

// ---------------------------------------------------------------------------
// Merged neighbor encoder with uint8 tables (at the random 128B-row-gather
// demand-bandwidth floor: 268MB / ~41.5us = 6.45 TB/s delivered).
__global__ __launch_bounds__(256) void k_neighbor(
    const int* __restrict__ q_l1, const int* __restrict__ q_l2,
    const int* __restrict__ q_r1, const int* __restrict__ q_r2,
    const int* __restrict__ s_l1, const int* __restrict__ s_l2,
    const int* __restrict__ s_r1, const int* __restrict__ s_r2,
    const u8* __restrict__ pr, const u8* __restrict__ pe,
    const float* __restrict__ srel, const float* __restrict__ sent,
    const float* __restrict__ gcn_wb, const float* __restrict__ gcn_b,
    const float* __restrict__ hop_gate,
    float* __restrict__ qn, float* __restrict__ sn, bf16u* __restrict__ XX)
{
  const int b = blockIdx.x, t = threadIdx.x;
  const int *cA, *cB; float* outp; bf16u* xxp; int n, coloff;
  if (b < 4096)      { cA = q_l1; cB = q_l2; n = b;        outp = qn; xxp = XX; coloff = 0; }
  else if (b < 8192) { cA = q_r1; cB = q_r2; n = b - 4096; outp = qn; xxp = XX; coloff = 128; }
  else if (b < 8197) { cA = s_l1; cB = s_l2; n = b - 8192; outp = sn; xxp = 0;  coloff = 0; }
  else               { cA = s_r1; cB = s_r2; n = b - 8197; outp = sn; xxp = 0;  coloff = 128; }

  __shared__ float wS[2][64];
  __shared__ float red[256][17];

  const int hop = t >> 7, g = (t >> 3) & 15, p = t & 7;
  const int* connG = hop ? cB : cA;

  int2 pairs[4];
  #pragma unroll
  for (int kk = 0; kk < 4; ++kk)
    pairs[kk] = *(const int2*)&connG[(n * 64 + g + (kk << 4)) * 2];

  float vR = 0.f, vE = 0.f;
  if (t < 128) {
    const int sh = t >> 6, nn = t & 63;
    const int* connS = sh ? cB : cA;
    int2 sp = *(const int2*)&connS[(n * 64 + nn) * 2];
    vR = srel[sp.x];
    vE = sent[sp.y];
  }

  uint4 ra[4], rb[4];
  #pragma unroll
  for (int kk = 0; kk < 4; ++kk) {
    ra[kk] = *(const uint4*)&pr[(size_t)pairs[kk].x * 128 + p * 16];
    rb[kk] = *(const uint4*)&pe[(size_t)pairs[kk].y * 128 + p * 16];
  }

  if (t < 128) {
    const int sh = t >> 6, nn = t & 63;
    float sc = vR + vE;
    float m = sc;
    #pragma unroll
    for (int off = 32; off; off >>= 1) m = fmaxf(m, __shfl_xor(m, off, 64));
    float e = __expf(sc - m);
    float s = e;
    #pragma unroll
    for (int off = 32; off; off >>= 1) s += __shfl_xor(s, off, 64);
    wS[sh][nn] = e / s;
  }
  __syncthreads();

  float a[16];
  #pragma unroll
  for (int c = 0; c < 16; ++c) a[c] = 0.f;
  #pragma unroll
  for (int kk = 0; kk < 4; ++kk) {
    const float wk = wS[hop][g + (kk << 4)];
    const uint4 A = ra[kk], Bv = rb[kk];
    a[0]  += wk * (ub0(A.x) + ub0(Bv.x));
    a[1]  += wk * (ub1(A.x) + ub1(Bv.x));
    a[2]  += wk * (ub2(A.x) + ub2(Bv.x));
    a[3]  += wk * (ub3(A.x) + ub3(Bv.x));
    a[4]  += wk * (ub0(A.y) + ub0(Bv.y));
    a[5]  += wk * (ub1(A.y) + ub1(Bv.y));
    a[6]  += wk * (ub2(A.y) + ub2(Bv.y));
    a[7]  += wk * (ub3(A.y) + ub3(Bv.y));
    a[8]  += wk * (ub0(A.z) + ub0(Bv.z));
    a[9]  += wk * (ub1(A.z) + ub1(Bv.z));
    a[10] += wk * (ub2(A.z) + ub2(Bv.z));
    a[11] += wk * (ub3(A.z) + ub3(Bv.z));
    a[12] += wk * (ub0(A.w) + ub0(Bv.w));
    a[13] += wk * (ub1(A.w) + ub1(Bv.w));
    a[14] += wk * (ub2(A.w) + ub2(Bv.w));
    a[15] += wk * (ub3(A.w) + ub3(Bv.w));
  }
  #pragma unroll
  for (int c = 0; c < 16; ++c) red[t][c] = a[c];
  __syncthreads();

  if (t < 128) {
    const int d = t, pp = d >> 4, cc = d & 15;
    float sA = 0.f, sB = 0.f;
    #pragma unroll
    for (int gg = 0; gg < 16; ++gg) {
      sA += red[gg * 8 + pp][cc];
      sB += red[128 + gg * 8 + pp][cc];
    }
    float accA = sA * (1.f / 512.f) - 0.5f;
    float accB = sB * (1.f / 512.f) - 0.5f;
    float bias = gcn_wb[d] + gcn_b[d];
    float g0 = hop_gate[0], g1 = hop_gate[1];
    float mx = fmaxf(g0, g1);
    float e0 = __expf(g0 - mx), e1 = __expf(g1 - mx);
    float inv = 1.f / (e0 + e1);
    float v = e0 * inv * tanhf_(bias + accA) + e1 * inv * tanhf_(bias + accB);
    outp[n * 256 + coloff + d] = v;
    if (xxp) xxp[(size_t)n * 576 + coloff + d] = f2b(v);
  }
}

// ---------------------------------------------------------------------------
// Support encoder layer 1: 40 blocks (8 per row) -- parallel, latency-hidden.
// (Round-5 5-block fusion was a -10us regression: 0.2% occupancy.)
__global__ __launch_bounds__(256) void k_sup1(
    const float* __restrict__ sn, const float* __restrict__ p1_w,
    const float* __restrict__ p1_b, float* __restrict__ h1)
{
  const int r = blockIdx.x >> 3, j0 = (blockIdx.x & 7) << 6;
  const int t = threadIdx.x;
  __shared__ float xs[256];
  xs[t] = sn[r * 256 + t];
  __syncthreads();
  const int j = j0 + (t >> 2), q = t & 3;
  const float* wr = p1_w + (size_t)j * 256 + q * 64;
  float acc = 0.f;
  #pragma unroll
  for (int k = 0; k < 64; ++k) acc += xs[q * 64 + k] * wr[k];
  acc += __shfl_xor(acc, 1, 64);
  acc += __shfl_xor(acc, 2, 64);
  if (q == 0) h1[r * 512 + j] = fmaxf(acc + p1_b[j], 0.f);
}

__global__ __launch_bounds__(256) void k_sup2(
    const float* __restrict__ sn, const float* __restrict__ h1,
    const float* __restrict__ p2_w, const float* __restrict__ p2_b,
    const float* __restrict__ ln_g, const float* __restrict__ ln_b,
    float* __restrict__ sg)
{
  const int r = blockIdx.x, t = threadIdx.x;
  const int lane = t & 63, wave = t >> 6;
  __shared__ float hs[512];
  __shared__ float zs[256];
  __shared__ float r1[4], r2[4];
  hs[t] = h1[r * 512 + t];
  hs[t + 256] = h1[r * 512 + 256 + t];
  __syncthreads();
  const int q = t & 3;
  #pragma unroll
  for (int jc = 0; jc < 4; ++jc) {
    int j = jc * 64 + (t >> 2);
    const float* wr = p2_w + (size_t)j * 512 + q * 128;
    float acc = 0.f;
    #pragma unroll
    for (int k = 0; k < 128; ++k) acc += hs[q * 128 + k] * wr[k];
    acc += __shfl_xor(acc, 1, 64);
    acc += __shfl_xor(acc, 2, 64);
    if (q == 0) zs[j] = acc + p2_b[j] + sn[r * 256 + j];
  }
  __syncthreads();
  float v = zs[t];
  float s1 = v, s2 = v * v;
  #pragma unroll
  for (int off = 32; off; off >>= 1) { s1 += __shfl_xor(s1, off, 64); s2 += __shfl_xor(s2, off, 64); }
  if (lane == 0) { r1[wave] = s1; r2[wave] = s2; }
  __syncthreads();
  float S1 = r1[0] + r1[1] + r1[2] + r1[3];
  float S2 = r2[0] + r2[1] + r2[2] + r2[3];
  float mu = S1 * (1.f / 256.f);
  float var = S2 * (1.f / 256.f) - mu * mu;
  sg[r * 256 + t] = (v - mu) * rsqrtf(var + 1e-6f) * ln_g[t] + ln_b[t];
}

// ---------------------------------------------------------------------------
// gates (bf16, stride 2048, cols 0..1791) = XX @ WW.T + bsum, MFMA 16x16x32.
// BK=64, gload_lds direct staging (rule #21). LDS 64KB. sg2 folded in as a
// block-uniform prologue on blocks 0..31 of the step-0 launch (WWb/sm are
// consumed only by LATER launches -> race-free).
__global__ __launch_bounds__(256) void k_gates_mfma(
    const bf16u* __restrict__ XX, const bf16u* __restrict__ WW,
    const float* __restrict__ bsum, bf16u* __restrict__ gates, int kchunks,
    const float* __restrict__ sg, const float* __restrict__ w_hh,
    bf16u* __restrict__ WWbo, float* __restrict__ sm, int dosg2)
{
  const int t = threadIdx.x;
  const int wave = t >> 6, lane = t & 63;
  const int quad = lane >> 4, l16 = lane & 15;
  const int wm = (wave >> 1) << 6, wn = (wave & 1) << 6;
  const int lin = (blockIdx.x & 7) * 56 + (blockIdx.x >> 3);
  const int row0 = (lin / 14) << 7;
  const int col0 = (lin % 14) << 7;
  __shared__ short As[2][128][64];
  __shared__ short Bs[2][128][64];

  if (dosg2 && blockIdx.x < 32) {   // block-uniform branch: barriers legal
    float (*s5)[256] = (float(*)[256])&As[0][0][0];   // 5KB overlay on As
    const int blk = blockIdx.x;
    for (int i = t; i < 1280; i += 256) s5[i >> 8][i & 255] = sg[i];
    __syncthreads();
    if (blk == 0)
      sm[t] = (s5[0][t] + s5[1][t] + s5[2][t] + s5[3][t] + s5[4][t]) * 0.2f;
    const int j = (blk << 6) + (t >> 2), q = t & 3;
    const float4* wr = (const float4*)(w_hh + (size_t)j * 512 + 256 + q * 64);
    float a[5] = {0.f, 0.f, 0.f, 0.f, 0.f};
    #pragma unroll
    for (int kk = 0; kk < 16; ++kk) {
      float4 w = wr[kk];
      int k = q * 64 + kk * 4;
      #pragma unroll
      for (int r = 0; r < 5; ++r)
        a[r] += s5[r][k] * w.x + s5[r][k+1] * w.y + s5[r][k+2] * w.z + s5[r][k+3] * w.w;
    }
    #pragma unroll
    for (int r = 0; r < 5; ++r) {
      a[r] += __shfl_xor(a[r], 1, 64);
      a[r] += __shfl_xor(a[r], 2, 64);
    }
    if (q == 0) {
      #pragma unroll
      for (int r = 0; r < 5; ++r)
        WWbo[(size_t)j * 576 + 512 + r] = f2b(a[r]);
    }
    __syncthreads();   // protect overlay before staging overwrites As
  }

  f32x4 acc[4][4];
  #pragma unroll
  for (int i = 0; i < 4; ++i)
    #pragma unroll
    for (int j = 0; j < 4; ++j) acc[i][j] = (f32x4){0.f, 0.f, 0.f, 0.f};

  int offX[4], offW[4];
  #pragma unroll
  for (int e = 0; e < 4; ++e) {
    int row = wave * 32 + e * 8 + (lane >> 3);
    int sw = (lane & 7) ^ (lane >> 3);
    offX[e] = (row0 + row) * 576 + sw * 8;
    offW[e] = (col0 + row) * 576 + sw * 8;
  }
  char* aBase = (char*)&As[0][0][0] + wave * 4096;
  char* bBase = (char*)&Bs[0][0][0] + wave * 4096;

  #define STAGE(buf, kc)                                                      \
    {                                                                         \
      const int kof_ = (kc) * 64;                                             \
      _Pragma("unroll")                                                       \
      for (int e = 0; e < 4; ++e) {                                           \
        GLOAD16(XX + offX[e] + kof_, aBase + (buf) * 16384 + e * 1024);       \
        GLOAD16(WW + offW[e] + kof_, bBase + (buf) * 16384 + e * 1024);       \
      }                                                                       \
    }

  STAGE(0, 0);
  __syncthreads();   // drains vmcnt -> buf 0 visible

  for (int kc = 0; kc < kchunks; ++kc) {
    const int cur = kc & 1;
    if (kc + 1 < kchunks) STAGE(cur ^ 1, kc + 1);
    #pragma unroll
    for (int kc2 = 0; kc2 < 2; ++kc2) {
      bf16x8 af[4], bfr[4];
      #pragma unroll
      for (int i = 0; i < 4; ++i)
        af[i] = *(const bf16x8*)&As[cur][wm + i * 16 + l16]
                                       [(((kc2 << 2) + quad) ^ (l16 & 7)) << 3];
      #pragma unroll
      for (int j = 0; j < 4; ++j)
        bfr[j] = *(const bf16x8*)&Bs[cur][wn + j * 16 + l16]
                                        [(((kc2 << 2) + quad) ^ (l16 & 7)) << 3];
      #pragma unroll
      for (int i = 0; i < 4; ++i)
        #pragma unroll
        for (int j = 0; j < 4; ++j)
          acc[i][j] = __builtin_amdgcn_mfma_f32_16x16x32_bf16(af[i], bfr[j], acc[i][j], 0, 0, 0);
    }
    __syncthreads();
  }
  #undef STAGE

  #pragma unroll
  for (int j = 0; j < 4; ++j) {
    const int col = col0 + wn + j * 16 + l16;
    const float bs = bsum[col];
    #pragma unroll
    for (int i = 0; i < 4; ++i) {
      #pragma unroll
      for (int r = 0; r < 4; ++r) {
        int row = row0 + wm + i * 16 + quad * 4 + r;
        gates[(size_t)row * 2048 + col] = f2b(acc[i][j][r] + bs);
      }
    }
  }
}

// ---------------------------------------------------------------------------
// Cell pointwise + attention (fused 5-way reduction, 1 barrier).
// Step 3 skips the dead c-store.
__global__ __launch_bounds__(256) void k_cell(
    const bf16u* __restrict__ gates, const float* __restrict__ qn,
    float* __restrict__ c, bf16u* __restrict__ XX,
    const float* __restrict__ sg, const float* __restrict__ sm,
    float* __restrict__ out, int step)
{
  __shared__ float red[4][6];
  const int b = blockIdx.x, t = threadIdx.x;
  const int lane = t & 63, wave = t >> 6;
  const bf16u* g = gates + (size_t)b * 2048;
  float i0 = b2f(g[t]),       f0 = b2f(g[512 + t]), gg0 = b2f(g[1024 + t]), o0 = b2f(g[1536 + t]);
  float i1 = b2f(g[256 + t]), f1 = b2f(g[768 + t]), gg1 = b2f(g[1280 + t]);
  float co0 = step ? c[b * 512 + t] : 0.f;
  float co1 = step ? c[b * 512 + 256 + t] : 0.f;
  float c0 = sigmoidf_(f0) * co0 + sigmoidf_(i0) * tanhf_(gg0);
  float c1 = sigmoidf_(f1) * co1 + sigmoidf_(i1) * tanhf_(gg1);
  if (step < 3) {
    c[b * 512 + t] = c0;
    c[b * 512 + 256 + t] = c1;
  }
  float hcv = sigmoidf_(o0) * tanhf_(c0);
  float h = qn[b * 256 + t] + hcv;
  if (step < 3) {
    XX[(size_t)b * 576 + 256 + t] = f2b(hcv);
    float dots[5];
    #pragma unroll
    for (int s = 0; s < 5; ++s) dots[s] = h * sg[s * 256 + t];
    #pragma unroll
    for (int off = 32; off; off >>= 1) {
      #pragma unroll
      for (int s = 0; s < 5; ++s) dots[s] += __shfl_xor(dots[s], off, 64);
    }
    if (lane == 0) {
      #pragma unroll
      for (int s = 0; s < 5; ++s) red[wave][s] = dots[s];
    }
    __syncthreads();
    #pragma unroll
    for (int s = 0; s < 5; ++s)
      dots[s] = red[0][s] + red[1][s] + red[2][s] + red[3][s];
    float m = dots[0];
    #pragma unroll
    for (int s = 1; s < 5; ++s) m = fmaxf(m, dots[s]);
    float sum = 0.f;
    #pragma unroll
    for (int s = 0; s < 5; ++s) sum += __expf(dots[s] - m);
    if (t < 5) {
      float dv = (t == 1) ? dots[1] : (t == 2) ? dots[2] : (t == 3) ? dots[3]
               : (t == 4) ? dots[4] : dots[0];
      XX[(size_t)b * 576 + 512 + t] = f2b(__expf(dv - m) / sum);
    }
  } else {
    float v = h * sm[t];
    #pragma unroll
    for (int off = 32; off; off >>= 1) v += __shfl_xor(v, off, 64);
    if (lane == 0) red[wave][0] = v;
    __syncthreads();
    if (t == 0) out[b] = red[0][0] + red[1][0] + red[2][0] + red[3][0];
  }
}

// ---------------------------------------------------------------------------
extern "C" void kernel_launch(void* const* d_in, const int* in_sizes, int n_in,
                              void* d_out, int out_size, void* d_ws, size_t ws_size,
                              hipStream_t stream)
{
  (void)in_sizes; (void)n_in; (void)out_size; (void)ws_size;
  const int *q_l1 = (const int*)d_in[0], *q_l2 = (const int*)d_in[1];
  const int *q_r1 = (const int*)d_in[2], *q_r2 = (const int*)d_in[3];
  const int *s_l1 = (const int*)d_in[4], *s_l2 = (const int*)d_in[5];
  const int *s_r1 = (const int*)d_in[6], *s_r2 = (const int*)d_in[7];
  const float* emb      = (const float*)d_in[12];
  const float* gcn_w    = (const float*)d_in[13];
  const float* gcn_wb   = (const float*)d_in[14];
  const float* gcn_b    = (const float*)d_in[15];
  const float* hop_gate = (const float*)d_in[16];
  const float* attn_w   = (const float*)d_in[17];
  const float* p1_w = (const float*)d_in[19];
  const float* p1_b = (const float*)d_in[20];
  const float* p2_w = (const float*)d_in[21];
  const float* p2_b = (const float*)d_in[22];
  const float* ln_g = (const float*)d_in[23];
  const float* ln_b = (const float*)d_in[24];
  const float* w_ih = (const float*)d_in[25];
  const float* w_hh = (const float*)d_in[26];
  const float* b_ih = (const float*)d_in[27];
  const float* b_hh = (const float*)d_in[28];

  char* base = (char*)d_ws;
  size_t off = 0;
  auto alloc = [&](size_t bytes) -> char* {
    char* r = base + off;
    off = (off + bytes + 255) & ~(size_t)255;
    return r;
  };
  u8* pr       = (u8*)alloc(100001ull * 128);
  u8* pe       = (u8*)alloc(100001ull * 128);
  float* srel  = (float*)alloc(100001ull * 4);
  float* sent  = (float*)alloc(100001ull * 4);
  float* qn    = (float*)alloc(4096ull * 256 * 4);
  float* sn    = (float*)alloc(5 * 256 * 4);
  float* sg    = (float*)alloc(5 * 256 * 4);
  float* sm    = (float*)alloc(256 * 4);
  float* h1b   = (float*)alloc(5 * 512 * 4);
  bf16u* XX    = (bf16u*)alloc(4096ull * 576 * 2);
  bf16u* WWa   = (bf16u*)alloc(2048ull * 576 * 2);
  bf16u* WWb   = (bf16u*)alloc(2048ull * 576 * 2);
  float* bsum  = (float*)alloc(2048 * 4);
  bf16u* gates = (bf16u*)alloc(4096ull * 2048 * 2);
  float* cbuf  = (float*)alloc(4096ull * 512 * 4);

  k_front<<<3611, 256, 0, stream>>>(emb, gcn_w, attn_w, w_ih, w_hh, b_ih, b_hh,
                                    pr, pe, srel, sent, WWa, WWb, bsum, XX);
  k_neighbor<<<8202, 256, 0, stream>>>(q_l1, q_l2, q_r1, q_r2, s_l1, s_l2, s_r1, s_r2,
                                       pr, pe, srel, sent, gcn_wb, gcn_b, hop_gate,
                                       qn, sn, XX);
  k_sup1<<<40, 256, 0, stream>>>(sn, p1_w, p1_b, h1b);
  k_sup2<<<5, 256, 0, stream>>>(sn, h1b, p2_w, p2_b, ln_g, ln_b, sg);

  for (int step = 0; step < 4; ++step) {
    if (step == 0)
      k_gates_mfma<<<448, 256, 0, stream>>>(XX, WWa, bsum, gates, 4,
                                            sg, w_hh, WWb, sm, 1);
    else
      k_gates_mfma<<<448, 256, 0, stream>>>(XX, WWb, bsum, gates, 9,
                                            sg, w_hh, WWb, sm, 0);
    k_cell<<<4096, 256, 0, stream>>>(gates, qn, cbuf, XX, sg, sm, (float*)d_out, step);
  }
}

// Round 7
// 321.947 us; speedup vs baseline: 1.0725x; 1.0337x over previous
//
#include <hip/hip_runtime.h>

typedef unsigned short bf16u;
typedef unsigned char u8;
typedef unsigned int u32;
typedef float f32x4 __attribute__((ext_vector_type(4)));
typedef short bf16x8 __attribute__((ext_vector_type(8)));

__device__ inline float sigmoidf_(float x) { return 1.f / (1.f + __expf(-x)); }
__device__ inline float tanhf_(float x) {
  // fast tanh: 1 - 2/(e^{2x}+1); |err| ~1e-6, saturates correctly at +-inf
  float e = __expf(2.f * x);
  return 1.f - 2.f / (e + 1.f);
}
__device__ inline float b2f(bf16u u) { return __uint_as_float(((u32)u) << 16); }
__device__ inline bf16u f2b(float f) {
  u32 i = __float_as_uint(f);
  u32 r = (i + 0x7fffu + ((i >> 16) & 1u)) >> 16;
  return (bf16u)r;
}
// uint8 table codec: stored = clamp(round(v*512 + 128)); decoded = u/512 - 0.25
__device__ inline u8 enc8(float v) {
  float q = fmaf(v, 512.f, 128.5f);
  q = fminf(fmaxf(q, 0.f), 255.f);
  return (u8)(int)q;
}
__device__ inline float ub0(u32 u) { return (float)(u & 0xffu); }
__device__ inline float ub1(u32 u) { return (float)((u >> 8) & 0xffu); }
__device__ inline float ub2(u32 u) { return (float)((u >> 16) & 0xffu); }
__device__ inline float ub3(u32 u) { return (float)(u >> 24); }

// async global->LDS, 16B per lane; LDS dest is wave-uniform base + lane*16
#define GLOAD16(gsrc, ldst)                                                   \
  __builtin_amdgcn_global_load_lds(                                           \
      (const __attribute__((address_space(1))) void*)(gsrc),                  \
      (__attribute__((address_space(3))) void*)(ldst), 16, 0, 0)

// ---------------------------------------------------------------------------
// k_vprep: one-time gcn_w f32 -> bf16 conversion into Vp, PRE-SWIZZLED with
// the ds_read involution (phys slot qs of row r holds logical slot qs^(r&15))
// so k_front can stage it with global_load_lds into a LINEAR LDS dest and
// read fragments conflict-free (rule #21). 4096 threads, ~2us.
__global__ __launch_bounds__(256) void k_vprep(
    const float* __restrict__ gcn_w, bf16u* __restrict__ Vp)
{
  const int g = blockIdx.x * 256 + threadIdx.x;   // [0, 4096) 16B slots
  const int half = g >> 11, rem = g & 2047;       // 2048 slots per half
  const int r = rem >> 4, qs = rem & 15;
  const int ls = qs ^ (r & 15);
  const float* src = gcn_w + r * 256 + half * 128 + ls * 8;
  float4 v0 = *(const float4*)src;
  float4 v1 = *(const float4*)(src + 4);
  ushort4 p0, p1;
  p0.x = f2b(v0.x); p0.y = f2b(v0.y); p0.z = f2b(v0.z); p0.w = f2b(v0.w);
  p1.x = f2b(v1.x); p1.y = f2b(v1.y); p1.z = f2b(v1.z); p1.w = f2b(v1.w);
  *(ushort4*)(Vp + (size_t)g * 8) = p0;
  *(ushort4*)(Vp + (size_t)g * 8 + 4) = p1;
}

// ---------------------------------------------------------------------------
// k_front: heterogeneous blocks, one launch.
//   blocks 0..1562   : pr/pe table build. v7:
//     - B staged via global_load_lds from pre-swizzled Vp (no per-block f32
//       load + f2b conversion VALU; B traffic halved to bf16)
//     - srel/sent computed FROM THE ACCUMULATORS (emb*(B^T aw) = (emb*B^T)*aw)
//       -> the two serial 128-deep us phases and the 32-iter scores loop are
//       deleted; replaced by 32 fma + 4 shfl reduces + 2KB LDS partials.
//   blocks 1563..3610: LSTM weight pack (WWa/WWb/bsum) + XX pad-zero.
__global__ __launch_bounds__(256) void k_front(
    const float* __restrict__ emb, const bf16u* __restrict__ Vp,
    const float* __restrict__ attn_w,
    const float* __restrict__ w_ih, const float* __restrict__ w_hh,
    const float* __restrict__ b_ih, const float* __restrict__ b_hh,
    u8* __restrict__ pr, u8* __restrict__ pe,
    float* __restrict__ srel, float* __restrict__ sent,
    bf16u* __restrict__ WWa, bf16u* __restrict__ WWb, float* __restrict__ bsum,
    bf16u* __restrict__ XX)
{
  const int blk = blockIdx.x, t = threadIdx.x;
  if (blk >= 1563) {
    const int b = blk - 1563;   // 0..2047
    if (t < 59) {
      XX[(size_t)b * 576 + 517 + t] = 0;
      XX[(size_t)(b + 2048) * 576 + 517 + t] = 0;
    }
    float wi = w_ih[b * 256 + t];
    float wh = w_hh[b * 512 + t];
    WWa[(size_t)b * 576 + t] = f2b(wi);
    WWb[(size_t)b * 576 + t] = f2b(wi + wh);
    WWb[(size_t)b * 576 + 256 + t] = f2b(wh);
    if (t < 59) WWb[(size_t)b * 576 + 517 + t] = 0;
    if (t == 0) bsum[b] = b_ih[b] + b_hh[b];
    return;
  }
  // ---- pr/pe table build ----
  const int row0 = blk << 6;
  __shared__ short As[64][136];
  __shared__ union PB {
    short B[128][128];      // linear dest for gload_lds (swizzle baked in Vp)
    u8 ob[64][272];
  } pb;
  __shared__ float scp[2][2][64];   // [rel/ent][wn-half][row]

  const int wave = t >> 6, lane = t & 63;
  const int quad = lane >> 4, l16 = lane & 15;
  const int wm = (wave >> 1) << 5, wn = (wave & 1) << 6;

  // stage B half 0 via gload_lds: 2048 slots of 16B, 8 per thread
  {
    char* lbase = (char*)&pb.B[0][0] + wave * 8192;
    #pragma unroll
    for (int e = 0; e < 8; ++e) {
      int s = wave * 512 + e * 64 + lane;
      GLOAD16(Vp + (size_t)s * 8, lbase + e * 1024);
    }
  }
  // stage As: emb rows (f32 -> bf16; emb is unique per block, must convert)
  #pragma unroll
  for (int s = 0; s < 8; ++s) {
    int f = s * 256 + t;
    int row = f >> 5, q = f & 31;
    int gr = row0 + row; if (gr > 100000) gr = 100000;
    float4 v = *(const float4*)&emb[(size_t)gr * 128 + (q << 2)];
    ushort4 pk;
    pk.x = f2b(v.x); pk.y = f2b(v.y); pk.z = f2b(v.z); pk.w = f2b(v.w);
    *(ushort4*)&As[row][q << 2] = pk;
  }
  // attn_w fragment for the acc-based scores (L2-resident, 512B)
  float aw[4];
  #pragma unroll
  for (int j = 0; j < 4; ++j) aw[j] = attn_w[wn + j * 16 + l16];

  f32x4 acc0[2][4], acc1[2][4];
  #pragma unroll
  for (int i = 0; i < 2; ++i)
    #pragma unroll
    for (int j = 0; j < 4; ++j) {
      acc0[i][j] = (f32x4){0.f, 0.f, 0.f, 0.f};
      acc1[i][j] = (f32x4){0.f, 0.f, 0.f, 0.f};
    }
  __syncthreads();   // drains gload vmcnt + As writes
  #pragma unroll
  for (int kc = 0; kc < 4; ++kc) {
    bf16x8 af[2], bfr[4];
    #pragma unroll
    for (int i = 0; i < 2; ++i)
      af[i] = *(const bf16x8*)&As[wm + i * 16 + l16][kc * 32 + quad * 8];
    #pragma unroll
    for (int j = 0; j < 4; ++j)
      bfr[j] = *(const bf16x8*)&pb.B[wn + j * 16 + l16]
                                    [((kc * 4 + quad) ^ l16) * 8];
    #pragma unroll
    for (int i = 0; i < 2; ++i)
      #pragma unroll
      for (int j = 0; j < 4; ++j)
        acc0[i][j] = __builtin_amdgcn_mfma_f32_16x16x32_bf16(af[i], bfr[j], acc0[i][j], 0, 0, 0);
  }
  __syncthreads();   // all B0 reads done
  // stage B half 1
  {
    char* lbase = (char*)&pb.B[0][0] + wave * 8192;
    #pragma unroll
    for (int e = 0; e < 8; ++e) {
      int s = wave * 512 + e * 64 + lane;
      GLOAD16(Vp + 16384 + (size_t)s * 8, lbase + e * 1024);
    }
  }
  __syncthreads();   // drains gload vmcnt
  #pragma unroll
  for (int kc = 0; kc < 4; ++kc) {
    bf16x8 af[2], bfr[4];
    #pragma unroll
    for (int i = 0; i < 2; ++i)
      af[i] = *(const bf16x8*)&As[wm + i * 16 + l16][kc * 32 + quad * 8];
    #pragma unroll
    for (int j = 0; j < 4; ++j)
      bfr[j] = *(const bf16x8*)&pb.B[wn + j * 16 + l16]
                                    [((kc * 4 + quad) ^ l16) * 8];
    #pragma unroll
    for (int i = 0; i < 2; ++i)
      #pragma unroll
      for (int j = 0; j < 4; ++j)
        acc1[i][j] = __builtin_amdgcn_mfma_f32_16x16x32_bf16(af[i], bfr[j], acc1[i][j], 0, 0, 0);
  }
  // scores from accumulators: per (i,r) row, dot over this wave's 64 cols,
  // reduce across l16 (masks 1,2,4,8 stay within the 16-lane quad group)
  {
    #pragma unroll
    for (int i = 0; i < 2; ++i) {
      #pragma unroll
      for (int r = 0; r < 4; ++r) {
        float t0 = acc0[i][0][r] * aw[0] + acc0[i][1][r] * aw[1] +
                   acc0[i][2][r] * aw[2] + acc0[i][3][r] * aw[3];
        float t1 = acc1[i][0][r] * aw[0] + acc1[i][1][r] * aw[1] +
                   acc1[i][2][r] * aw[2] + acc1[i][3][r] * aw[3];
        #pragma unroll
        for (int m = 1; m < 16; m <<= 1) {
          t0 += __shfl_xor(t0, m, 64);
          t1 += __shfl_xor(t1, m, 64);
        }
        if (l16 == 0) {
          int row = wm + i * 16 + quad * 4 + r;
          scp[0][wn >> 6][row] = t0;
          scp[1][wn >> 6][row] = t1;
        }
      }
    }
  }
  __syncthreads();   // B1 reads done everywhere + scp visible
  // enc8 epilogue -> ob (aliases pb.B; safe after the barrier)
  #pragma unroll
  for (int j = 0; j < 4; ++j) {
    const int col = wn + j * 16 + l16;
    #pragma unroll
    for (int i = 0; i < 2; ++i) {
      #pragma unroll
      for (int r = 0; r < 4; ++r) {
        int row = wm + i * 16 + quad * 4 + r;
        pb.ob[row][col] = enc8(acc0[i][j][r]);
        pb.ob[row][128 + col] = enc8(acc1[i][j][r]);
      }
    }
  }
  if (t < 64) {
    int gr = row0 + t;
    if (gr <= 100000) {
      srel[gr] = scp[0][0][t] + scp[0][1][t];
      sent[gr] = scp[1][0][t] + scp[1][1][t];
    }
  }
  __syncthreads();
  #pragma unroll
  for (int s = 0; s < 4; ++s) {
    int c = s * 256 + t;
    int row = c >> 4, part = c & 15;
    int gr = row0 + row;
    if (gr <= 100000) {
      uint4 v = *(const uint4*)&pb.ob[row][part * 16];
      if (part < 8) *(uint4*)&pr[(size_t)gr * 128 + part * 16] = v;
      else          *(uint4*)&pe[(size_t)gr * 128 + (part - 8) * 16] = v;
    }
  }
}

// ---------------------------------------------------------------------------
// Merged neighbor encoder with uint8 tables (at the random 128B-row-gather
// demand-bandwidth floor: 268MB / ~41.5us = 6.45 TB/s delivered).
__global__ __launch_bounds__(256) void k_neighbor(
    const int* __restrict__ q_l1, const int* __restrict__ q_l2,
    const int* __restrict__ q_r1, const int* __restrict__ q_r2,
    const int* __restrict__ s_l1, const int* __restrict__ s_l2,
    const int* __restrict__ s_r1, const int* __restrict__ s_r2,
    const u8* __restrict__ pr, const u8* __restrict__ pe,
    const float* __restrict__ srel, const float* __restrict__ sent,
    const float* __restrict__ gcn_wb, const float* __restrict__ gcn_b,
    const float* __restrict__ hop_gate,
    float* __restrict__ qn, float* __restrict__ sn, bf16u* __restrict__ XX)
{
  const int b = blockIdx.x, t = threadIdx.x;
  const int *cA, *cB; float* outp; bf16u* xxp; int n, coloff;
  if (b < 4096)      { cA = q_l1; cB = q_l2; n = b;        outp = qn; xxp = XX; coloff = 0; }
  else if (b < 8192) { cA = q_r1; cB = q_r2; n = b - 4096; outp = qn; xxp = XX; coloff = 128; }
  else if (b < 8197) { cA = s_l1; cB = s_l2; n = b - 8192; outp = sn; xxp = 0;  coloff = 0; }
  else               { cA = s_r1; cB = s_r2; n = b - 8197; outp = sn; xxp = 0;  coloff = 128; }

  __shared__ float wS[2][64];
  __shared__ float red[256][17];

  const int hop = t >> 7, g = (t >> 3) & 15, p = t & 7;
  const int* connG = hop ? cB : cA;

  int2 pairs[4];
  #pragma unroll
  for (int kk = 0; kk < 4; ++kk)
    pairs[kk] = *(const int2*)&connG[(n * 64 + g + (kk << 4)) * 2];

  float vR = 0.f, vE = 0.f;
  if (t < 128) {
    const int sh = t >> 6, nn = t & 63;
    const int* connS = sh ? cB : cA;
    int2 sp = *(const int2*)&connS[(n * 64 + nn) * 2];
    vR = srel[sp.x];
    vE = sent[sp.y];
  }

  uint4 ra[4], rb[4];
  #pragma unroll
  for (int kk = 0; kk < 4; ++kk) {
    ra[kk] = *(const uint4*)&pr[(size_t)pairs[kk].x * 128 + p * 16];
    rb[kk] = *(const uint4*)&pe[(size_t)pairs[kk].y * 128 + p * 16];
  }

  if (t < 128) {
    const int sh = t >> 6, nn = t & 63;
    float sc = vR + vE;
    float m = sc;
    #pragma unroll
    for (int off = 32; off; off >>= 1) m = fmaxf(m, __shfl_xor(m, off, 64));
    float e = __expf(sc - m);
    float s = e;
    #pragma unroll
    for (int off = 32; off; off >>= 1) s += __shfl_xor(s, off, 64);
    wS[sh][nn] = e / s;
  }
  __syncthreads();

  float a[16];
  #pragma unroll
  for (int c = 0; c < 16; ++c) a[c] = 0.f;
  #pragma unroll
  for (int kk = 0; kk < 4; ++kk) {
    const float wk = wS[hop][g + (kk << 4)];
    const uint4 A = ra[kk], Bv = rb[kk];
    a[0]  += wk * (ub0(A.x) + ub0(Bv.x));
    a[1]  += wk * (ub1(A.x) + ub1(Bv.x));
    a[2]  += wk * (ub2(A.x) + ub2(Bv.x));
    a[3]  += wk * (ub3(A.x) + ub3(Bv.x));
    a[4]  += wk * (ub0(A.y) + ub0(Bv.y));
    a[5]  += wk * (ub1(A.y) + ub1(Bv.y));
    a[6]  += wk * (ub2(A.y) + ub2(Bv.y));
    a[7]  += wk * (ub3(A.y) + ub3(Bv.y));
    a[8]  += wk * (ub0(A.z) + ub0(Bv.z));
    a[9]  += wk * (ub1(A.z) + ub1(Bv.z));
    a[10] += wk * (ub2(A.z) + ub2(Bv.z));
    a[11] += wk * (ub3(A.z) + ub3(Bv.z));
    a[12] += wk * (ub0(A.w) + ub0(Bv.w));
    a[13] += wk * (ub1(A.w) + ub1(Bv.w));
    a[14] += wk * (ub2(A.w) + ub2(Bv.w));
    a[15] += wk * (ub3(A.w) + ub3(Bv.w));
  }
  #pragma unroll
  for (int c = 0; c < 16; ++c) red[t][c] = a[c];
  __syncthreads();

  if (t < 128) {
    const int d = t, pp = d >> 4, cc = d & 15;
    float sA = 0.f, sB = 0.f;
    #pragma unroll
    for (int gg = 0; gg < 16; ++gg) {
      sA += red[gg * 8 + pp][cc];
      sB += red[128 + gg * 8 + pp][cc];
    }
    float accA = sA * (1.f / 512.f) - 0.5f;
    float accB = sB * (1.f / 512.f) - 0.5f;
    float bias = gcn_wb[d] + gcn_b[d];
    float g0 = hop_gate[0], g1 = hop_gate[1];
    float mx = fmaxf(g0, g1);
    float e0 = __expf(g0 - mx), e1 = __expf(g1 - mx);
    float inv = 1.f / (e0 + e1);
    float v = e0 * inv * tanhf_(bias + accA) + e1 * inv * tanhf_(bias + accB);
    outp[n * 256 + coloff + d] = v;
    if (xxp) xxp[(size_t)n * 576 + coloff + d] = f2b(v);
  }
}

// ---------------------------------------------------------------------------
// Support encoder layer 1: 40 blocks (8 per row) -- parallel, latency-hidden.
__global__ __launch_bounds__(256) void k_sup1(
    const float* __restrict__ sn, const float* __restrict__ p1_w,
    const float* __restrict__ p1_b, float* __restrict__ h1)
{
  const int r = blockIdx.x >> 3, j0 = (blockIdx.x & 7) << 6;
  const int t = threadIdx.x;
  __shared__ float xs[256];
  xs[t] = sn[r * 256 + t];
  __syncthreads();
  const int j = j0 + (t >> 2), q = t & 3;
  const float* wr = p1_w + (size_t)j * 256 + q * 64;
  float acc = 0.f;
  #pragma unroll
  for (int k = 0; k < 64; ++k) acc += xs[q * 64 + k] * wr[k];
  acc += __shfl_xor(acc, 1, 64);
  acc += __shfl_xor(acc, 2, 64);
  if (q == 0) h1[r * 512 + j] = fmaxf(acc + p1_b[j], 0.f);
}

__global__ __launch_bounds__(256) void k_sup2(
    const float* __restrict__ sn, const float* __restrict__ h1,
    const float* __restrict__ p2_w, const float* __restrict__ p2_b,
    const float* __restrict__ ln_g, const float* __restrict__ ln_b,
    float* __restrict__ sg)
{
  const int r = blockIdx.x, t = threadIdx.x;
  const int lane = t & 63, wave = t >> 6;
  __shared__ float hs[512];
  __shared__ float zs[256];
  __shared__ float r1[4], r2[4];
  hs[t] = h1[r * 512 + t];
  hs[t + 256] = h1[r * 512 + 256 + t];
  __syncthreads();
  const int q = t & 3;
  #pragma unroll
  for (int jc = 0; jc < 4; ++jc) {
    int j = jc * 64 + (t >> 2);
    const float* wr = p2_w + (size_t)j * 512 + q * 128;
    float acc = 0.f;
    #pragma unroll
    for (int k = 0; k < 128; ++k) acc += hs[q * 128 + k] * wr[k];
    acc += __shfl_xor(acc, 1, 64);
    acc += __shfl_xor(acc, 2, 64);
    if (q == 0) zs[j] = acc + p2_b[j] + sn[r * 256 + j];
  }
  __syncthreads();
  float v = zs[t];
  float s1 = v, s2 = v * v;
  #pragma unroll
  for (int off = 32; off; off >>= 1) { s1 += __shfl_xor(s1, off, 64); s2 += __shfl_xor(s2, off, 64); }
  if (lane == 0) { r1[wave] = s1; r2[wave] = s2; }
  __syncthreads();
  float S1 = r1[0] + r1[1] + r1[2] + r1[3];
  float S2 = r2[0] + r2[1] + r2[2] + r2[3];
  float mu = S1 * (1.f / 256.f);
  float var = S2 * (1.f / 256.f) - mu * mu;
  sg[r * 256 + t] = (v - mu) * rsqrtf(var + 1e-6f) * ln_g[t] + ln_b[t];
}

// ---------------------------------------------------------------------------
// gates (bf16, stride 2048, cols 0..1791) = XX @ WW.T + bsum, MFMA 16x16x32.
// BK=64, gload_lds direct staging (rule #21). LDS 64KB. sg2 folded in as a
// block-uniform prologue on blocks 0..31 of the step-0 launch (WWb/sm are
// consumed only by LATER launches -> race-free).
__global__ __launch_bounds__(256) void k_gates_mfma(
    const bf16u* __restrict__ XX, const bf16u* __restrict__ WW,
    const float* __restrict__ bsum, bf16u* __restrict__ gates, int kchunks,
    const float* __restrict__ sg, const float* __restrict__ w_hh,
    bf16u* __restrict__ WWbo, float* __restrict__ sm, int dosg2)
{
  const int t = threadIdx.x;
  const int wave = t >> 6, lane = t & 63;
  const int quad = lane >> 4, l16 = lane & 15;
  const int wm = (wave >> 1) << 6, wn = (wave & 1) << 6;
  const int lin = (blockIdx.x & 7) * 56 + (blockIdx.x >> 3);
  const int row0 = (lin / 14) << 7;
  const int col0 = (lin % 14) << 7;
  __shared__ short As[2][128][64];
  __shared__ short Bs[2][128][64];

  if (dosg2 && blockIdx.x < 32) {   // block-uniform branch: barriers legal
    float (*s5)[256] = (float(*)[256])&As[0][0][0];   // 5KB overlay on As
    const int blk = blockIdx.x;
    for (int i = t; i < 1280; i += 256) s5[i >> 8][i & 255] = sg[i];
    __syncthreads();
    if (blk == 0)
      sm[t] = (s5[0][t] + s5[1][t] + s5[2][t] + s5[3][t] + s5[4][t]) * 0.2f;
    const int j = (blk << 6) + (t >> 2), q = t & 3;
    const float4* wr = (const float4*)(w_hh + (size_t)j * 512 + 256 + q * 64);
    float a[5] = {0.f, 0.f, 0.f, 0.f, 0.f};
    #pragma unroll
    for (int kk = 0; kk < 16; ++kk) {
      float4 w = wr[kk];
      int k = q * 64 + kk * 4;
      #pragma unroll
      for (int r = 0; r < 5; ++r)
        a[r] += s5[r][k] * w.x + s5[r][k+1] * w.y + s5[r][k+2] * w.z + s5[r][k+3] * w.w;
    }
    #pragma unroll
    for (int r = 0; r < 5; ++r) {
      a[r] += __shfl_xor(a[r], 1, 64);
      a[r] += __shfl_xor(a[r], 2, 64);
    }
    if (q == 0) {
      #pragma unroll
      for (int r = 0; r < 5; ++r)
        WWbo[(size_t)j * 576 + 512 + r] = f2b(a[r]);
    }
    __syncthreads();   // protect overlay before staging overwrites As
  }

  f32x4 acc[4][4];
  #pragma unroll
  for (int i = 0; i < 4; ++i)
    #pragma unroll
    for (int j = 0; j < 4; ++j) acc[i][j] = (f32x4){0.f, 0.f, 0.f, 0.f};

  int offX[4], offW[4];
  #pragma unroll
  for (int e = 0; e < 4; ++e) {
    int row = wave * 32 + e * 8 + (lane >> 3);
    int sw = (lane & 7) ^ (lane >> 3);
    offX[e] = (row0 + row) * 576 + sw * 8;
    offW[e] = (col0 + row) * 576 + sw * 8;
  }
  char* aBase = (char*)&As[0][0][0] + wave * 4096;
  char* bBase = (char*)&Bs[0][0][0] + wave * 4096;

  #define STAGE(buf, kc)                                                      \
    {                                                                         \
      const int kof_ = (kc) * 64;                                             \
      _Pragma("unroll")                                                       \
      for (int e = 0; e < 4; ++e) {                                           \
        GLOAD16(XX + offX[e] + kof_, aBase + (buf) * 16384 + e * 1024);       \
        GLOAD16(WW + offW[e] + kof_, bBase + (buf) * 16384 + e * 1024);       \
      }                                                                       \
    }

  STAGE(0, 0);
  __syncthreads();   // drains vmcnt -> buf 0 visible

  for (int kc = 0; kc < kchunks; ++kc) {
    const int cur = kc & 1;
    if (kc + 1 < kchunks) STAGE(cur ^ 1, kc + 1);
    #pragma unroll
    for (int kc2 = 0; kc2 < 2; ++kc2) {
      bf16x8 af[4], bfr[4];
      #pragma unroll
      for (int i = 0; i < 4; ++i)
        af[i] = *(const bf16x8*)&As[cur][wm + i * 16 + l16]
                                       [(((kc2 << 2) + quad) ^ (l16 & 7)) << 3];
      #pragma unroll
      for (int j = 0; j < 4; ++j)
        bfr[j] = *(const bf16x8*)&Bs[cur][wn + j * 16 + l16]
                                        [(((kc2 << 2) + quad) ^ (l16 & 7)) << 3];
      #pragma unroll
      for (int i = 0; i < 4; ++i)
        #pragma unroll
        for (int j = 0; j < 4; ++j)
          acc[i][j] = __builtin_amdgcn_mfma_f32_16x16x32_bf16(af[i], bfr[j], acc[i][j], 0, 0, 0);
    }
    __syncthreads();
  }
  #undef STAGE

  #pragma unroll
  for (int j = 0; j < 4; ++j) {
    const int col = col0 + wn + j * 16 + l16;
    const float bs = bsum[col];
    #pragma unroll
    for (int i = 0; i < 4; ++i) {
      #pragma unroll
      for (int r = 0; r < 4; ++r) {
        int row = row0 + wm + i * 16 + quad * 4 + r;
        gates[(size_t)row * 2048 + col] = f2b(acc[i][j][r] + bs);
      }
    }
  }
}

// ---------------------------------------------------------------------------
// Cell pointwise + attention (fused 5-way reduction, 1 barrier).
// Step 3 skips the dead c-store.
__global__ __launch_bounds__(256) void k_cell(
    const bf16u* __restrict__ gates, const float* __restrict__ qn,
    float* __restrict__ c, bf16u* __restrict__ XX,
    const float* __restrict__ sg, const float* __restrict__ sm,
    float* __restrict__ out, int step)
{
  __shared__ float red[4][6];
  const int b = blockIdx.x, t = threadIdx.x;
  const int lane = t & 63, wave = t >> 6;
  const bf16u* g = gates + (size_t)b * 2048;
  float i0 = b2f(g[t]),       f0 = b2f(g[512 + t]), gg0 = b2f(g[1024 + t]), o0 = b2f(g[1536 + t]);
  float i1 = b2f(g[256 + t]), f1 = b2f(g[768 + t]), gg1 = b2f(g[1280 + t]);
  float co0 = step ? c[b * 512 + t] : 0.f;
  float co1 = step ? c[b * 512 + 256 + t] : 0.f;
  float c0 = sigmoidf_(f0) * co0 + sigmoidf_(i0) * tanhf_(gg0);
  float c1 = sigmoidf_(f1) * co1 + sigmoidf_(i1) * tanhf_(gg1);
  if (step < 3) {
    c[b * 512 + t] = c0;
    c[b * 512 + 256 + t] = c1;
  }
  float hcv = sigmoidf_(o0) * tanhf_(c0);
  float h = qn[b * 256 + t] + hcv;
  if (step < 3) {
    XX[(size_t)b * 576 + 256 + t] = f2b(hcv);
    float dots[5];
    #pragma unroll
    for (int s = 0; s < 5; ++s) dots[s] = h * sg[s * 256 + t];
    #pragma unroll
    for (int off = 32; off; off >>= 1) {
      #pragma unroll
      for (int s = 0; s < 5; ++s) dots[s] += __shfl_xor(dots[s], off, 64);
    }
    if (lane == 0) {
      #pragma unroll
      for (int s = 0; s < 5; ++s) red[wave][s] = dots[s];
    }
    __syncthreads();
    #pragma unroll
    for (int s = 0; s < 5; ++s)
      dots[s] = red[0][s] + red[1][s] + red[2][s] + red[3][s];
    float m = dots[0];
    #pragma unroll
    for (int s = 1; s < 5; ++s) m = fmaxf(m, dots[s]);
    float sum = 0.f;
    #pragma unroll
    for (int s = 0; s < 5; ++s) sum += __expf(dots[s] - m);
    if (t < 5) {
      float dv = (t == 1) ? dots[1] : (t == 2) ? dots[2] : (t == 3) ? dots[3]
               : (t == 4) ? dots[4] : dots[0];
      XX[(size_t)b * 576 + 512 + t] = f2b(__expf(dv - m) / sum);
    }
  } else {
    float v = h * sm[t];
    #pragma unroll
    for (int off = 32; off; off >>= 1) v += __shfl_xor(v, off, 64);
    if (lane == 0) red[wave][0] = v;
    __syncthreads();
    if (t == 0) out[b] = red[0][0] + red[1][0] + red[2][0] + red[3][0];
  }
}

// ---------------------------------------------------------------------------
extern "C" void kernel_launch(void* const* d_in, const int* in_sizes, int n_in,
                              void* d_out, int out_size, void* d_ws, size_t ws_size,
                              hipStream_t stream)
{
  (void)in_sizes; (void)n_in; (void)out_size; (void)ws_size;
  const int *q_l1 = (const int*)d_in[0], *q_l2 = (const int*)d_in[1];
  const int *q_r1 = (const int*)d_in[2], *q_r2 = (const int*)d_in[3];
  const int *s_l1 = (const int*)d_in[4], *s_l2 = (const int*)d_in[5];
  const int *s_r1 = (const int*)d_in[6], *s_r2 = (const int*)d_in[7];
  const float* emb      = (const float*)d_in[12];
  const float* gcn_w    = (const float*)d_in[13];
  const float* gcn_wb   = (const float*)d_in[14];
  const float* gcn_b    = (const float*)d_in[15];
  const float* hop_gate = (const float*)d_in[16];
  const float* attn_w   = (const float*)d_in[17];
  const float* p1_w = (const float*)d_in[19];
  const float* p1_b = (const float*)d_in[20];
  const float* p2_w = (const float*)d_in[21];
  const float* p2_b = (const float*)d_in[22];
  const float* ln_g = (const float*)d_in[23];
  const float* ln_b = (const float*)d_in[24];
  const float* w_ih = (const float*)d_in[25];
  const float* w_hh = (const float*)d_in[26];
  const float* b_ih = (const float*)d_in[27];
  const float* b_hh = (const float*)d_in[28];

  char* base = (char*)d_ws;
  size_t off = 0;
  auto alloc = [&](size_t bytes) -> char* {
    char* r = base + off;
    off = (off + bytes + 255) & ~(size_t)255;
    return r;
  };
  u8* pr       = (u8*)alloc(100001ull * 128);
  u8* pe       = (u8*)alloc(100001ull * 128);
  float* srel  = (float*)alloc(100001ull * 4);
  float* sent  = (float*)alloc(100001ull * 4);
  bf16u* Vp    = (bf16u*)alloc(2ull * 16384 * 2);
  float* qn    = (float*)alloc(4096ull * 256 * 4);
  float* sn    = (float*)alloc(5 * 256 * 4);
  float* sg    = (float*)alloc(5 * 256 * 4);
  float* sm    = (float*)alloc(256 * 4);
  float* h1b   = (float*)alloc(5 * 512 * 4);
  bf16u* XX    = (bf16u*)alloc(4096ull * 576 * 2);
  bf16u* WWa   = (bf16u*)alloc(2048ull * 576 * 2);
  bf16u* WWb   = (bf16u*)alloc(2048ull * 576 * 2);
  float* bsum  = (float*)alloc(2048 * 4);
  bf16u* gates = (bf16u*)alloc(4096ull * 2048 * 2);
  float* cbuf  = (float*)alloc(4096ull * 512 * 4);

  k_vprep<<<16, 256, 0, stream>>>(gcn_w, Vp);
  k_front<<<3611, 256, 0, stream>>>(emb, Vp, attn_w, w_ih, w_hh, b_ih, b_hh,
                                    pr, pe, srel, sent, WWa, WWb, bsum, XX);
  k_neighbor<<<8202, 256, 0, stream>>>(q_l1, q_l2, q_r1, q_r2, s_l1, s_l2, s_r1, s_r2,
                                       pr, pe, srel, sent, gcn_wb, gcn_b, hop_gate,
                                       qn, sn, XX);
  k_sup1<<<40, 256, 0, stream>>>(sn, p1_w, p1_b, h1b);
  k_sup2<<<5, 256, 0, stream>>>(sn, h1b, p2_w, p2_b, ln_g, ln_b, sg);

  for (int step = 0; step < 4; ++step) {
    if (step == 0)
      k_gates_mfma<<<448, 256, 0, stream>>>(XX, WWa, bsum, gates, 4,
                                            sg, w_hh, WWb, sm, 1);
    else
      k_gates_mfma<<<448, 256, 0, stream>>>(XX, WWb, bsum, gates, 9,
                                            sg, w_hh, WWb, sm, 0);
    k_cell<<<4096, 256, 0, stream>>>(gates, qn, cbuf, XX, sg, sm, (float*)d_out, step);
  }
}